// Round 14
// baseline (191.062 us; speedup 1.0000x reference)
//
#include <hip/hip_runtime.h>
#include <hip/hip_bf16.h>
#include <hip/hip_fp8.h>

typedef unsigned char u8;
typedef __attribute__((ext_vector_type(4))) float f32x4;
typedef __attribute__((ext_vector_type(4))) int   i32x4;
typedef __attribute__((ext_vector_type(8))) int   i32x8;

#define NROWS 8192   // B*N = 128*64
#define DDIM  256    // feature dim

// ---------------- Kernel 1: L2-normalize rows, f32 -> fp8 e4m3 ----------------
__global__ __launch_bounds__(256) void norm_kernel(const float* __restrict__ in,
                                                   u8* __restrict__ out) {
    int tid = threadIdx.x;
    int wave = tid >> 6, lane = tid & 63;
    int row = blockIdx.x * 4 + wave;                 // 2048 blocks * 4 rows
    float4 v = ((const float4*)(in + (size_t)row * DDIM))[lane];
    float ss = v.x * v.x + v.y * v.y + v.z * v.z + v.w * v.w;
    #pragma unroll
    for (int m = 1; m < 64; m <<= 1) ss += __shfl_xor(ss, m, 64);
    float sc = 1.0f / fmaxf(sqrtf(ss), 1e-12f);
    __hip_fp8_e4m3 q0(v.x * sc), q1(v.y * sc), q2(v.z * sc), q3(v.w * sc);
    unsigned pk = (unsigned)q0.__x | ((unsigned)q1.__x << 8) |
                  ((unsigned)q2.__x << 16) | ((unsigned)q3.__x << 24);
    ((unsigned*)out)[row * 64 + lane] = pk;          // 4 fp8 bytes per lane
}

// ---------------- Kernel 2: Gram + exp + register-accumulated row sums --------
// Grid 512 = 64 row-panels (p: 128 rows) x 8 col-groups (jg: 1024 cols).
// 512 threads = 8 waves (2 wr x 4 wc); wave tile 64 rows x 32 cols.
// A panel (128x256B fp8) staged once, A-frags held in REGISTERS for all steps.
// B: 8 col-tiles of 128, double-buffered LDS, counted vmcnt(4) pipeline (R9-proven).
// Row sums accumulate in registers across all 8 steps; ONE plain store per row
// per slice at block end -> ZERO atomics, zero init passes, even 2-round grid.
// pos: snapshot at step s* = p&7 in block jg == p>>3, waves with wc>>1 == wr.
// MFMA: mfma_scale_f32_16x16x128_f8f6f4, unit scales. Swizzle per rule 21.
#define CFENCE asm volatile("" ::: "memory")

template <int SEL>
__device__ inline float dpp_shr_add(float x) {
    int y = __builtin_amdgcn_update_dpp(0, __float_as_int(x), SEL, 0xf, 0xf, true);
    return x + __int_as_float(y);
}

__device__ inline float dpp_reduce16(float x) {
    x = dpp_shr_add<0x111>(x);
    x = dpp_shr_add<0x112>(x);
    x = dpp_shr_add<0x114>(x);
    x = dpp_shr_add<0x118>(x);   // lane c==15 of each 16-group holds the sum
    return x;
}

__global__ __launch_bounds__(512) void sim_kernel(const u8* __restrict__ f8,
                                                  float* __restrict__ part,
                                                  float* __restrict__ pos_slice) {
    __shared__ u8 lA[128 * 256];      // 32 KB A panel (full K)
    __shared__ u8 lB[2][128 * 256];   // 64 KB B double buffer

    const int tid  = threadIdx.x;
    const int lane = tid & 63;
    const int wave = tid >> 6;        // 0..7
    const int wr = wave >> 2;         // 0..1 : rows wr*64 .. +63  (one 64-batch)
    const int wc = wave & 3;          // 0..3 : cols wc*32 .. +31

    const int jg = blockIdx.x & 7;    // col group (XCD-affine: bid%8 -> XCD)
    const int p  = blockIdx.x >> 3;   // row panel
    const int arow0 = p * 128;
    const int bcol0 = jg * 1024;

    // stage helpers: 4 x glds(16B)/thread; panels [128 rows][256 B], linear LDS dest,
    // inverse-swizzled source col (XOR (r&7)<<4 touches bits 4-6 only)
    #define STAGE(dst, grow0)                                                        \
        {                                                                            \
            _Pragma("unroll")                                                        \
            for (int i = 0; i < 4; ++i) {                                            \
                int o   = (i * 512 + tid) * 16;                                      \
                int r   = o >> 8;                                                    \
                int cb  = o & 255;                                                   \
                int scb = cb ^ ((r & 7) << 4);                                       \
                const u8* g = f8 + (size_t)((grow0) + r) * DDIM + scb;               \
                __builtin_amdgcn_global_load_lds(                                    \
                    (const __attribute__((address_space(1))) void*)g,                \
                    (__attribute__((address_space(3))) void*)((dst) + o), 16, 0, 0); \
            }                                                                        \
        }

    STAGE(lA, arow0);                  // A
    STAGE(lB[0], bcol0 + 0 * 128);     // B tile 0
    STAGE(lB[1], bcol0 + 1 * 128);     // B tile 1
    asm volatile("s_waitcnt vmcnt(4)" ::: "memory");   // A+B0 landed, B1 in flight
    __builtin_amdgcn_s_barrier();
    CFENCE;

    const int kb = (lane >> 4) << 5;   // lane-group's 32 k-bytes within 128-B chunk

    // ---- load A fragments into registers (once) ----
    i32x8 af[4][2];
    #pragma unroll
    for (int m = 0; m < 4; ++m) {
        int rA = wr * 64 + m * 16 + (lane & 15);
        int sw = (rA & 7) << 4;
        const u8* pr = lA + rA * 256;
        #pragma unroll
        for (int kc = 0; kc < 2; ++kc) {
            i32x4 lo = *(const i32x4*)(pr + ((kc * 128 + kb) ^ sw));
            i32x4 hi = *(const i32x4*)(pr + ((kc * 128 + kb + 16) ^ sw));
            af[m][kc][0] = lo[0]; af[m][kc][1] = lo[1]; af[m][kc][2] = lo[2]; af[m][kc][3] = lo[3];
            af[m][kc][4] = hi[0]; af[m][kc][5] = hi[1]; af[m][kc][6] = hi[2]; af[m][kc][7] = hi[3];
        }
    }

    float prs[4][4], pprs[4][4];
    #pragma unroll
    for (int m = 0; m < 4; ++m)
        #pragma unroll
        for (int j = 0; j < 4; ++j) { prs[m][j] = 0.f; pprs[m][j] = 0.f; }

    const int sstar = p & 7;                 // pos step (valid when jg == p>>3)
    const bool posw = (jg == (p >> 3)) && ((wc >> 1) == wr);

    #pragma unroll
    for (int s = 0; s < 8; ++s) {
        // ---- compute step s from lB[s&1] ----
        const u8* bB = lB[s & 1];
        i32x8 bv[2];
        #pragma unroll
        for (int n = 0; n < 2; ++n) {
            int rB = wc * 32 + n * 16 + (lane & 15);
            int sw = (rB & 7) << 4;
            const u8* pr = bB + rB * 256;
            i32x4 lo = *(const i32x4*)(pr + ((kb) ^ sw));
            i32x4 hi = *(const i32x4*)(pr + ((kb + 16) ^ sw));
            bv[n][0] = lo[0]; bv[n][1] = lo[1]; bv[n][2] = lo[2]; bv[n][3] = lo[3];
            bv[n][4] = hi[0]; bv[n][5] = hi[1]; bv[n][6] = hi[2]; bv[n][7] = hi[3];
        }
        f32x4 acc[4][2];
        #pragma unroll
        for (int m = 0; m < 4; ++m)
            #pragma unroll
            for (int n = 0; n < 2; ++n)
                acc[m][n] = (f32x4){0.f, 0.f, 0.f, 0.f};
        #pragma unroll
        for (int m = 0; m < 4; ++m)
            #pragma unroll
            for (int n = 0; n < 2; ++n)
                acc[m][n] = __builtin_amdgcn_mfma_scale_f32_16x16x128_f8f6f4(
                    af[m][0], bv[n], acc[m][n], 0, 0, 0, 0x7f7f7f7f, 0, 0x7f7f7f7f);
        // second K-chunk
        i32x8 bv2[2];
        #pragma unroll
        for (int n = 0; n < 2; ++n) {
            int rB = wc * 32 + n * 16 + (lane & 15);
            int sw = (rB & 7) << 4;
            const u8* pr = bB + rB * 256;
            i32x4 lo = *(const i32x4*)(pr + ((128 + kb) ^ sw));
            i32x4 hi = *(const i32x4*)(pr + ((128 + kb + 16) ^ sw));
            bv2[n][0] = lo[0]; bv2[n][1] = lo[1]; bv2[n][2] = lo[2]; bv2[n][3] = lo[3];
            bv2[n][4] = hi[0]; bv2[n][5] = hi[1]; bv2[n][6] = hi[2]; bv2[n][7] = hi[3];
        }
        #pragma unroll
        for (int m = 0; m < 4; ++m)
            #pragma unroll
            for (int n = 0; n < 2; ++n)
                acc[m][n] = __builtin_amdgcn_mfma_scale_f32_16x16x128_f8f6f4(
                    af[m][1], bv2[n], acc[m][n], 0, 0, 0, 0x7f7f7f7f, 0, 0x7f7f7f7f);

        // ---- per-step epilogue: exp + per-lane accumulate (no reduce yet) ----
        // C layout: col = lane&15 (+n*16), row = (lane>>4)*4 + j (+m*16)
        #pragma unroll
        for (int m = 0; m < 4; ++m)
            #pragma unroll
            for (int j = 0; j < 4; ++j) {
                float t = __expf(acc[m][0][j]) + __expf(acc[m][1][j]);
                prs[m][j] += t;
                if (posw && s == sstar) pprs[m][j] = t;
            }

        CFENCE;
        __builtin_amdgcn_s_barrier();            // all waves done reading lB[s&1]
        CFENCE;
        if (s + 2 <= 7) STAGE(lB[s & 1], bcol0 + (s + 2) * 128);  // restage freed buf
        if (s < 7) {
            if (s + 2 <= 7) { asm volatile("s_waitcnt vmcnt(4)" ::: "memory"); }
            else            { asm volatile("s_waitcnt vmcnt(0)" ::: "memory"); }
            __builtin_amdgcn_s_barrier();        // B(s+1) ready for all
            CFENCE;
        }
    }
    #undef STAGE

    // ---- block-end reduce (DPP, VALU-only) + single plain store per row ----
    const int g = lane >> 4;
    #pragma unroll
    for (int m = 0; m < 4; ++m)
        #pragma unroll
        for (int j = 0; j < 4; ++j) {
            prs[m][j] = dpp_reduce16(prs[m][j]);
            if (posw) pprs[m][j] = dpp_reduce16(pprs[m][j]);
        }
    if ((lane & 15) == 15) {
        float* slice = part + (size_t)(jg * 4 + wc) * NROWS;
        #pragma unroll
        for (int m = 0; m < 4; ++m)
            #pragma unroll
            for (int j = 0; j < 4; ++j) {
                int row = arow0 + wr * 64 + m * 16 + g * 4 + j;
                slice[row] = prs[m][j];
                if (posw) pos_slice[(size_t)(wc & 1) * NROWS + row] = pprs[m][j];
            }
    }
}

// ---------------- Kernel 3: loss = mean(log(total) - log(pos)) ----------------
__global__ __launch_bounds__(1024) void loss_kernel(const float* __restrict__ part,
                                                    const float* __restrict__ pos_slice,
                                                    float* __restrict__ out) {
    __shared__ float red[16];
    int tid = threadIdx.x;
    float s = 0.f;
    for (int r = tid; r < NROWS; r += 1024) {
        float tot = 0.f;
        #pragma unroll
        for (int i = 0; i < 32; ++i) tot += part[(size_t)i * NROWS + r];
        float pos = pos_slice[r] + pos_slice[NROWS + r];
        s += logf(tot) - logf(pos);
    }
    #pragma unroll
    for (int m = 1; m < 64; m <<= 1) s += __shfl_xor(s, m, 64);
    if ((tid & 63) == 0) red[tid >> 6] = s;
    __syncthreads();
    if (tid == 0) {
        float t = 0.f;
        #pragma unroll
        for (int i = 0; i < 16; ++i) t += red[i];
        out[0] = t * (1.0f / (float)NROWS);
    }
}

extern "C" void kernel_launch(void* const* d_in, const int* in_sizes, int n_in,
                              void* d_out, int out_size, void* d_ws, size_t ws_size,
                              hipStream_t stream) {
    const float* feat = (const float*)d_in[0];
    u8*    f8   = (u8*)d_ws;                                          // 2 MB
    float* part = (float*)((char*)d_ws + (size_t)NROWS * DDIM);       // 32*8192*4 = 1 MB
    float* pos  = part + 32 * NROWS;                                  // 2*8192*4 = 64 KB
    norm_kernel<<<dim3(NROWS / 4), dim3(256), 0, stream>>>(feat, f8);
    sim_kernel<<<dim3(512), dim3(512), 0, stream>>>(f8, part, pos);
    loss_kernel<<<dim3(1), dim3(1024), 0, stream>>>(part, pos, (float*)d_out);
}